// Round 2
// baseline (346.478 us; speedup 1.0000x reference)
//
#include <hip/hip_runtime.h>
#include <stdint.h>

#define BATCH 4096
#define NTX   4096   // NT*NX flattened sites
#define NH    2048   // N_HALF
#define KDIM  2048

#define BM 128
#define BN 128
#define BK 32

typedef __bf16 bf16x8 __attribute__((ext_vector_type(8)));
typedef float  f32x4  __attribute__((ext_vector_type(4)));

// RNE float -> bf16
__device__ __forceinline__ unsigned short f2bf(float f) {
    union { float f; unsigned u; } v; v.f = f;
    unsigned u = v.u;
    unsigned r = u + 0x7fffu + ((u >> 16) & 1u);
    return (unsigned short)(r >> 16);
}

__device__ __forceinline__ float fast_tanh(float x) {
    float e = __expf(x + x);
    return 1.f - 2.f / (e + 1.f);
}

typedef __attribute__((address_space(1))) void gvoid;
typedef __attribute__((address_space(3))) void lvoid;

__device__ __forceinline__ void async16(const unsigned short* g, unsigned short* l) {
    __builtin_amdgcn_global_load_lds((gvoid*)(void*)g, (lvoid*)l, 16, 0, 0);
}

// LDS element offset for tile row R (0..127), k-chunk c (0..3, 8 elems each),
// with XOR swizzle: slot column = (c + (R>>1)) & 3. Conflict-free b128 reads.
__device__ __forceinline__ int lds_off(int R, int c) {
    return R * BK + (((c) + (R >> 1)) & 3) * 8;
}

// ---------------------------------------------------------------------------
// prep: split phi -> B-half bf16; convert W_s, W_t -> bf16; zero logdet slots
// ---------------------------------------------------------------------------
__global__ void prep(const float* __restrict__ phi,
                     const float* __restrict__ Wsf,
                     const float* __restrict__ Wtf,
                     unsigned short* __restrict__ Bbf,
                     unsigned short* __restrict__ Wsb,
                     unsigned short* __restrict__ Wtb,
                     float* __restrict__ out)
{
    const int tid    = blockIdx.x * blockDim.x + threadIdx.x;
    const int stride = gridDim.x * blockDim.x;

    // B-half: phi[b][2i] -> Bbf[b][i]
    const float4* p4 = (const float4*)phi;
    for (int i = tid; i < (BATCH * NH / 4); i += stride) {
        float4 u = p4[2 * i], v = p4[2 * i + 1];
        uint2 o;
        o.x = (unsigned)f2bf(u.x) | ((unsigned)f2bf(u.z) << 16);
        o.y = (unsigned)f2bf(v.x) | ((unsigned)f2bf(v.z) << 16);
        ((uint2*)Bbf)[i] = o;
    }

    const float4* ws4 = (const float4*)Wsf;
    const float4* wt4 = (const float4*)Wtf;
    for (int i = tid; i < (NH * KDIM / 8); i += stride) {
        float4 u = ws4[2 * i], v = ws4[2 * i + 1];
        uint4 o;
        o.x = (unsigned)f2bf(u.x) | ((unsigned)f2bf(u.y) << 16);
        o.y = (unsigned)f2bf(u.z) | ((unsigned)f2bf(u.w) << 16);
        o.z = (unsigned)f2bf(v.x) | ((unsigned)f2bf(v.y) << 16);
        o.w = (unsigned)f2bf(v.z) | ((unsigned)f2bf(v.w) << 16);
        ((uint4*)Wsb)[i] = o;
        u = wt4[2 * i]; v = wt4[2 * i + 1];
        o.x = (unsigned)f2bf(u.x) | ((unsigned)f2bf(u.y) << 16);
        o.y = (unsigned)f2bf(u.z) | ((unsigned)f2bf(u.w) << 16);
        o.z = (unsigned)f2bf(v.x) | ((unsigned)f2bf(v.y) << 16);
        o.w = (unsigned)f2bf(v.z) | ((unsigned)f2bf(v.w) << 16);
        ((uint4*)Wtb)[i] = o;
    }

    // zero the logdet accumulation slots in d_out
    for (int i = tid; i < BATCH; i += stride) out[(size_t)BATCH * NTX + i] = 0.f;
}

// ---------------------------------------------------------------------------
// Dual GEMM + coupling epilogue (see R1). Swizzled LDS staging/reads.
// ---------------------------------------------------------------------------
__global__ __launch_bounds__(256, 2) void coupling_gemm(
    const unsigned short* __restrict__ X,
    const unsigned short* __restrict__ Wsb,
    const unsigned short* __restrict__ Wtb,
    const float* __restrict__ bs,
    const float* __restrict__ bt,
    const float* __restrict__ phi,
    float* __restrict__ out,
    unsigned short* __restrict__ Xout,
    int parity)
{
    __shared__ unsigned short Xs[BM * BK];
    __shared__ unsigned short Ss[BN * BK];
    __shared__ unsigned short Ts[BN * BK];

    const int tid = threadIdx.x;
    const int m0 = blockIdx.x * BM;
    const int n0 = blockIdx.y * BN;

    f32x4 acc_s[4][4], acc_t[4][4];
    const f32x4 zf = {0.f, 0.f, 0.f, 0.f};
#pragma unroll
    for (int i = 0; i < 4; i++)
#pragma unroll
        for (int j = 0; j < 4; j++) { acc_s[i][j] = zf; acc_t[i][j] = zf; }

    // staging: thread tid fills LDS slot (r=tid>>2, c_s=tid&3) [+64 rows for
    // chunk 2]. Global chunk fetched = (c_s - (r>>1)) & 3  (swizzle inverse).
    const int rowA = tid >> 2;
    const int cgl  = (((tid & 3) - ((tid >> 3) & 3)) & 3) * 8;  // global chunk elem off
    const unsigned short* Xg = X   + (size_t)(m0 + rowA) * KDIM + cgl;
    const unsigned short* Sg = Wsb + (size_t)(n0 + rowA) * KDIM + cgl;
    const unsigned short* Tg = Wtb + (size_t)(n0 + rowA) * KDIM + cgl;
    const size_t rstride = (size_t)64 * KDIM;
    unsigned short* Xl = Xs + tid * 8;
    unsigned short* Sl = Ss + tid * 8;
    unsigned short* Tl = Ts + tid * 8;

    const int wave = tid >> 6;
    const int lane = tid & 63;
    const int wm = (wave >> 1) * 64;
    const int wn = (wave & 1) * 64;
    const int lrow = lane & 15;
    const int kc   = lane >> 4;      // k-chunk 0..3

    for (int k0 = 0; k0 < KDIM; k0 += BK) {
        __syncthreads();
        async16(Xg + k0,           Xl);
        async16(Xg + k0 + rstride, Xl + 2048);
        async16(Sg + k0,           Sl);
        async16(Sg + k0 + rstride, Sl + 2048);
        async16(Tg + k0,           Tl);
        async16(Tg + k0 + rstride, Tl + 2048);
        __syncthreads();

        bf16x8 a[4], vs[4], vt[4];
#pragma unroll
        for (int i = 0; i < 4; i++) {
            a[i]  = *(const bf16x8*)(Xs + lds_off(wm + i * 16 + lrow, kc));
            vs[i] = *(const bf16x8*)(Ss + lds_off(wn + i * 16 + lrow, kc));
            vt[i] = *(const bf16x8*)(Ts + lds_off(wn + i * 16 + lrow, kc));
        }
#pragma unroll
        for (int mi = 0; mi < 4; mi++)
#pragma unroll
            for (int ni = 0; ni < 4; ni++) {
                acc_s[mi][ni] = __builtin_amdgcn_mfma_f32_16x16x32_bf16(
                    a[mi], vs[ni], acc_s[mi][ni], 0, 0, 0);
                acc_t[mi][ni] = __builtin_amdgcn_mfma_f32_16x16x32_bf16(
                    a[mi], vt[ni], acc_t[mi][ni], 0, 0, 0);
            }
    }

    // epilogue: C/D layout col=lane&15, row=(lane>>4)*4+reg
    float* ldslot = out + (size_t)BATCH * NTX;
#pragma unroll
    for (int mi = 0; mi < 4; mi++) {
#pragma unroll
        for (int r = 0; r < 4; r++) {
            const int brow = m0 + wm + mi * 16 + (lane >> 4) * 4 + r;
            float ssum = 0.f;
#pragma unroll
            for (int ni = 0; ni < 4; ni++) {
                const int n = n0 + wn + ni * 16 + lrow;
                float s  = fast_tanh(acc_s[mi][ni][r] + bs[n]);
                float tv = acc_t[mi][ni][r] + bt[n];
                const size_t oidx = (size_t)brow * NTX + 2 * n + parity;
                float val = fmaf(phi[oidx], __expf(s), tv);
                out[oidx] = val;
                if (Xout) Xout[(size_t)brow * NH + n] = f2bf(val);
                ssum += s;
            }
            ssum += __shfl_xor(ssum, 1);
            ssum += __shfl_xor(ssum, 2);
            ssum += __shfl_xor(ssum, 4);
            ssum += __shfl_xor(ssum, 8);
            if (lrow == 0) atomicAdd(ldslot + brow, ssum);
        }
    }
}

extern "C" void kernel_launch(void* const* d_in, const int* in_sizes, int n_in,
                              void* d_out, int out_size, void* d_ws, size_t ws_size,
                              hipStream_t stream) {
    const float* phi = (const float*)d_in[0];
    const float* Wsf = (const float*)d_in[1];
    const float* bs  = (const float*)d_in[2];
    const float* Wtf = (const float*)d_in[3];
    const float* bt  = (const float*)d_in[4];
    float* out = (float*)d_out;

    char* ws = (char*)d_ws;
    unsigned short* Bbf  = (unsigned short*)(ws);                 // 16 MiB
    unsigned short* Apbf = (unsigned short*)(ws + 16777216);      // 16 MiB
    unsigned short* Wsb  = (unsigned short*)(ws + 33554432);      //  8 MiB
    unsigned short* Wtb  = (unsigned short*)(ws + 41943040);      //  8 MiB

    prep<<<1024, 256, 0, stream>>>(phi, Wsf, Wtf, Bbf, Wsb, Wtb, out);

    // coupling 1: A' = A*exp(s(B)) + t(B)  (A at odd flat slots: parity=1)
    coupling_gemm<<<dim3(32, 16), 256, 0, stream>>>(
        Bbf, Wsb, Wtb, bs, bt, phi, out, Apbf, 1);

    // coupling 2: B' = B*exp(s(A')) + t(A') (B at even flat slots: parity=0)
    coupling_gemm<<<dim3(32, 16), 256, 0, stream>>>(
        Apbf, Wsb, Wtb, bs, bt, phi, out, nullptr, 0);
}

// Round 3
// 332.056 us; speedup vs baseline: 1.0434x; 1.0434x over previous
//
#include <hip/hip_runtime.h>
#include <stdint.h>

#define BATCH 4096
#define NTX   4096   // NT*NX flattened sites
#define NH    2048   // N_HALF
#define KDIM  2048

#define BM 128
#define BN 128
#define BK 32
#define TILE_E (BM * BK)   // 4096 elems = 8 KB per tile array

typedef __bf16 bf16x8 __attribute__((ext_vector_type(8)));
typedef float  f32x4  __attribute__((ext_vector_type(4)));

// RNE float -> bf16
__device__ __forceinline__ unsigned short f2bf(float f) {
    union { float f; unsigned u; } v; v.f = f;
    unsigned u = v.u;
    unsigned r = u + 0x7fffu + ((u >> 16) & 1u);
    return (unsigned short)(r >> 16);
}

__device__ __forceinline__ float fast_tanh(float x) {
    float e = __expf(x + x);
    return 1.f - 2.f / (e + 1.f);
}

typedef __attribute__((address_space(1))) void gvoid;
typedef __attribute__((address_space(3))) void lvoid;

__device__ __forceinline__ void async16(const unsigned short* g, unsigned short* l) {
    __builtin_amdgcn_global_load_lds((gvoid*)(void*)g, (lvoid*)l, 16, 0, 0);
}

// LDS element offset for tile row R (0..127), k-chunk c (0..3, 8 elems each),
// XOR swizzle: slot column = (c + (R>>1)) & 3. Conflict-free b128 reads (R2: verified 0 conflicts).
__device__ __forceinline__ int lds_off(int R, int c) {
    return R * BK + (((c) + (R >> 1)) & 3) * 8;
}

// ---------------------------------------------------------------------------
// prep: split phi -> B-half bf16; convert W_s, W_t -> bf16; zero logdet slots
// ---------------------------------------------------------------------------
__global__ void prep(const float* __restrict__ phi,
                     const float* __restrict__ Wsf,
                     const float* __restrict__ Wtf,
                     unsigned short* __restrict__ Bbf,
                     unsigned short* __restrict__ Wsb,
                     unsigned short* __restrict__ Wtb,
                     float* __restrict__ out)
{
    const int tid    = blockIdx.x * blockDim.x + threadIdx.x;
    const int stride = gridDim.x * blockDim.x;

    const float4* p4 = (const float4*)phi;
    for (int i = tid; i < (BATCH * NH / 4); i += stride) {
        float4 u = p4[2 * i], v = p4[2 * i + 1];
        uint2 o;
        o.x = (unsigned)f2bf(u.x) | ((unsigned)f2bf(u.z) << 16);
        o.y = (unsigned)f2bf(v.x) | ((unsigned)f2bf(v.z) << 16);
        ((uint2*)Bbf)[i] = o;
    }

    const float4* ws4 = (const float4*)Wsf;
    const float4* wt4 = (const float4*)Wtf;
    for (int i = tid; i < (NH * KDIM / 8); i += stride) {
        float4 u = ws4[2 * i], v = ws4[2 * i + 1];
        uint4 o;
        o.x = (unsigned)f2bf(u.x) | ((unsigned)f2bf(u.y) << 16);
        o.y = (unsigned)f2bf(u.z) | ((unsigned)f2bf(u.w) << 16);
        o.z = (unsigned)f2bf(v.x) | ((unsigned)f2bf(v.y) << 16);
        o.w = (unsigned)f2bf(v.z) | ((unsigned)f2bf(v.w) << 16);
        ((uint4*)Wsb)[i] = o;
        u = wt4[2 * i]; v = wt4[2 * i + 1];
        o.x = (unsigned)f2bf(u.x) | ((unsigned)f2bf(u.y) << 16);
        o.y = (unsigned)f2bf(u.z) | ((unsigned)f2bf(u.w) << 16);
        o.z = (unsigned)f2bf(v.x) | ((unsigned)f2bf(v.y) << 16);
        o.w = (unsigned)f2bf(v.z) | ((unsigned)f2bf(v.w) << 16);
        ((uint4*)Wtb)[i] = o;
    }

    for (int i = tid; i < BATCH; i += stride) out[(size_t)BATCH * NTX + i] = 0.f;
}

// ---------------------------------------------------------------------------
// Dual GEMM + coupling epilogue. Double-buffered LDS, ONE barrier per k-iter:
//   iter k: issue async loads tile k+1 -> buf[(k+1)&1]; compute on buf[k&1];
//           __syncthreads() (vmcnt(0) drain lands AFTER compute -> overlap).
// Barrier also protects buf reuse (all waves done reading before overwrite).
// ---------------------------------------------------------------------------
__global__ __launch_bounds__(256, 2) void coupling_gemm(
    const unsigned short* __restrict__ X,
    const unsigned short* __restrict__ Wsb,
    const unsigned short* __restrict__ Wtb,
    const float* __restrict__ bs,
    const float* __restrict__ bt,
    const float* __restrict__ phi,
    float* __restrict__ out,
    unsigned short* __restrict__ Xout,
    int parity)
{
    // [buf][array(X,S,T)][tile]
    __shared__ unsigned short lds[2][3][TILE_E];

    const int tid = threadIdx.x;
    const int m0 = blockIdx.x * BM;
    const int n0 = blockIdx.y * BN;

    f32x4 acc_s[4][4], acc_t[4][4];
    const f32x4 zf = {0.f, 0.f, 0.f, 0.f};
#pragma unroll
    for (int i = 0; i < 4; i++)
#pragma unroll
        for (int j = 0; j < 4; j++) { acc_s[i][j] = zf; acc_t[i][j] = zf; }

    // staging: thread tid fills LDS slot (r=tid>>2, c_s=tid&3) [+64 rows for
    // 2nd chunk]. Global chunk fetched = (c_s - (r>>1)) & 3 (swizzle inverse).
    const int rowA = tid >> 2;
    const int cgl  = (((tid & 3) - ((tid >> 3) & 3)) & 3) * 8;
    const unsigned short* Xg = X   + (size_t)(m0 + rowA) * KDIM + cgl;
    const unsigned short* Sg = Wsb + (size_t)(n0 + rowA) * KDIM + cgl;
    const unsigned short* Tg = Wtb + (size_t)(n0 + rowA) * KDIM + cgl;
    const size_t rstride = (size_t)64 * KDIM;
    const int lw = tid * 8;  // LDS write elem offset within a tile array

    const int wave = tid >> 6;
    const int lane = tid & 63;
    const int wm = (wave >> 1) * 64;
    const int wn = (wave & 1) * 64;
    const int lrow = lane & 15;
    const int kc   = lane >> 4;

    // prologue: stage tile 0 into buf 0
    {
        unsigned short* b = &lds[0][0][0];
        async16(Xg,           b + lw);
        async16(Xg + rstride, b + lw + 2048);
        b = &lds[0][1][0];
        async16(Sg,           b + lw);
        async16(Sg + rstride, b + lw + 2048);
        b = &lds[0][2][0];
        async16(Tg,           b + lw);
        async16(Tg + rstride, b + lw + 2048);
    }
    __syncthreads();

    const int NITER = KDIM / BK;   // 64
    for (int k = 0; k < NITER; k++) {
        const int cur = k & 1;
        const int nxt = cur ^ 1;
        // issue next tile's loads first (into the other buffer)
        {
            const int k0n = (k + 1 < NITER) ? (k + 1) * BK : 0;  // clamp: wasted but safe
            unsigned short* b = &lds[nxt][0][0];
            async16(Xg + k0n,           b + lw);
            async16(Xg + k0n + rstride, b + lw + 2048);
            b = &lds[nxt][1][0];
            async16(Sg + k0n,           b + lw);
            async16(Sg + k0n + rstride, b + lw + 2048);
            b = &lds[nxt][2][0];
            async16(Tg + k0n,           b + lw);
            async16(Tg + k0n + rstride, b + lw + 2048);
        }

        const unsigned short* Xs = &lds[cur][0][0];
        const unsigned short* Ss = &lds[cur][1][0];
        const unsigned short* Ts = &lds[cur][2][0];

        bf16x8 a[4], vs[4], vt[4];
#pragma unroll
        for (int i = 0; i < 4; i++) {
            a[i]  = *(const bf16x8*)(Xs + lds_off(wm + i * 16 + lrow, kc));
            vs[i] = *(const bf16x8*)(Ss + lds_off(wn + i * 16 + lrow, kc));
            vt[i] = *(const bf16x8*)(Ts + lds_off(wn + i * 16 + lrow, kc));
        }
#pragma unroll
        for (int mi = 0; mi < 4; mi++)
#pragma unroll
            for (int ni = 0; ni < 4; ni++) {
                acc_s[mi][ni] = __builtin_amdgcn_mfma_f32_16x16x32_bf16(
                    a[mi], vs[ni], acc_s[mi][ni], 0, 0, 0);
                acc_t[mi][ni] = __builtin_amdgcn_mfma_f32_16x16x32_bf16(
                    a[mi], vt[ni], acc_t[mi][ni], 0, 0, 0);
            }

        __syncthreads();  // drain (after compute) + buffer-reuse protection
    }

    // epilogue: C/D layout col=lane&15, row=(lane>>4)*4+reg
    float* ldslot = out + (size_t)BATCH * NTX;
#pragma unroll
    for (int mi = 0; mi < 4; mi++) {
#pragma unroll
        for (int r = 0; r < 4; r++) {
            const int brow = m0 + wm + mi * 16 + (lane >> 4) * 4 + r;
            float ssum = 0.f;
#pragma unroll
            for (int ni = 0; ni < 4; ni++) {
                const int n = n0 + wn + ni * 16 + lrow;
                float s  = fast_tanh(acc_s[mi][ni][r] + bs[n]);
                float tv = acc_t[mi][ni][r] + bt[n];
                const size_t oidx = (size_t)brow * NTX + 2 * n + parity;
                float val = fmaf(phi[oidx], __expf(s), tv);
                out[oidx] = val;
                if (Xout) Xout[(size_t)brow * NH + n] = f2bf(val);
                ssum += s;
            }
            ssum += __shfl_xor(ssum, 1);
            ssum += __shfl_xor(ssum, 2);
            ssum += __shfl_xor(ssum, 4);
            ssum += __shfl_xor(ssum, 8);
            if (lrow == 0) atomicAdd(ldslot + brow, ssum);
        }
    }
}

extern "C" void kernel_launch(void* const* d_in, const int* in_sizes, int n_in,
                              void* d_out, int out_size, void* d_ws, size_t ws_size,
                              hipStream_t stream) {
    const float* phi = (const float*)d_in[0];
    const float* Wsf = (const float*)d_in[1];
    const float* bs  = (const float*)d_in[2];
    const float* Wtf = (const float*)d_in[3];
    const float* bt  = (const float*)d_in[4];
    float* out = (float*)d_out;

    char* ws = (char*)d_ws;
    unsigned short* Bbf  = (unsigned short*)(ws);                 // 16 MiB
    unsigned short* Apbf = (unsigned short*)(ws + 16777216);      // 16 MiB
    unsigned short* Wsb  = (unsigned short*)(ws + 33554432);      //  8 MiB
    unsigned short* Wtb  = (unsigned short*)(ws + 41943040);      //  8 MiB

    prep<<<1024, 256, 0, stream>>>(phi, Wsf, Wtf, Bbf, Wsb, Wtb, out);

    // coupling 1: A' = A*exp(s(B)) + t(B)  (A at odd flat slots: parity=1)
    coupling_gemm<<<dim3(32, 16), 256, 0, stream>>>(
        Bbf, Wsb, Wtb, bs, bt, phi, out, Apbf, 1);

    // coupling 2: B' = B*exp(s(A')) + t(A') (B at even flat slots: parity=0)
    coupling_gemm<<<dim3(32, 16), 256, 0, stream>>>(
        Apbf, Wsb, Wtb, bs, bt, phi, out, nullptr, 0);
}